// Round 1
// baseline (1923.316 us; speedup 1.0000x reference)
//
#include <hip/hip_runtime.h>
#include <hip/hip_bf16.h>
#include <stdint.h>

// Problem constants
#define B_   32
#define L_   4096
#define C_   512
#define P_   128     // period
#define NP_  32      // L_/P_
#define D_   512     // d_model
#define M_   (B_*C_*NP_)   // 524288 GEMM rows

typedef __bf16  bf16x8  __attribute__((ext_vector_type(8)));
typedef float   floatx4 __attribute__((ext_vector_type(4)));

// round-to-nearest-even f32 -> bf16, pack two into a dword (lo = first)
__device__ inline uint32_t pack_bf16(float lo, float hi) {
    uint32_t ulo = __float_as_uint(lo);
    uint32_t uhi = __float_as_uint(hi);
    ulo += 0x7FFFu + ((ulo >> 16) & 1u);
    uhi += 0x7FFFu + ((uhi >> 16) & 1u);
    return (ulo >> 16) | (uhi & 0xFFFF0000u);
}

// ---------------------------------------------------------------------------
// Kernel 0: W [p][d] f32 -> Wt [d][p] bf16  (B-operand layout: k-contiguous)
// ---------------------------------------------------------------------------
__global__ __launch_bounds__(256) void wt_kernel(const float* __restrict__ W,
                                                 uint16_t* __restrict__ Wt) {
    int tid = blockIdx.x * 256 + threadIdx.x;    // 65536 total
    int d = tid >> 7;
    int p = tid & 127;
    uint32_t u = __float_as_uint(W[p * D_ + d]);
    u += 0x7FFFu + ((u >> 16) & 1u);
    Wt[tid] = (uint16_t)(u >> 16);
}

// ---------------------------------------------------------------------------
// Kernel 1: EMA trend + season, chunked with 128-step warm-up.
// grid = 32 b * 2 c-halves * 16 l-chunks = 1024 blocks, 256 threads = 1 channel each.
// Writes trend f32 [b][c][l] and season bf16 scratch [r=(b,c,n)][p] (reg-transposed).
// ---------------------------------------------------------------------------
__global__ __launch_bounds__(256) void ema_kernel(const float* __restrict__ x,
                                                  const float* __restrict__ alpha,
                                                  float* __restrict__ trend_out,
                                                  uint32_t* __restrict__ season_ws) {
    int bid   = blockIdx.x;
    int chunk = bid & 15;          // l-chunk of 256
    int chalf = (bid >> 4) & 1;    // which 256 channels
    int b     = bid >> 5;
    int c     = chalf * 256 + threadIdx.x;
    int l0    = chunk << 8;
    int lstart = (chunk == 0) ? 0 : (l0 - 128);

    const float a = alpha[c];
    const float e = 1.0f - a;
    const float* xp = x + (size_t)b * L_ * C_ + c;     // stride C_ per l

    // init + warm-up (truncation error ~0.7^128 ~ 1.6e-20)
    float tr = xp[(size_t)lstart * C_];
    #pragma unroll 8
    for (int l = lstart + 1; l < l0; ++l) {
        float xv = xp[(size_t)l * C_];
        tr = fmaf(e, tr, a * xv);
    }

    float* tp = trend_out + ((size_t)(b * C_ + c)) * L_;
    uint32_t packbuf[16];

    for (int f = 0; f < 8; ++f) {              // 8 flushes of 32 steps
        int lb = l0 + f * 32;
        #pragma unroll
        for (int j = 0; j < 32; j += 2) {
            float xv0 = xp[(size_t)(lb + j) * C_];
            float xv1 = xp[(size_t)(lb + j + 1) * C_];
            tr = fmaf(e, tr, a * xv0);
            float s0 = xv0 - tr;
            tp[lb + j] = tr;
            tr = fmaf(e, tr, a * xv1);
            float s1 = xv1 - tr;
            tp[lb + j + 1] = tr;
            packbuf[j >> 1] = pack_bf16(s0, s1);
        }
        int n  = lb >> 7;           // period index
        int p0 = lb & 127;          // 0,32,64,96
        uint32_t* dst = season_ws
            + ((size_t)((b * C_ + c) * NP_ + n)) * (P_ / 2) + (p0 >> 1);
        #pragma unroll
        for (int q = 0; q < 4; ++q) {
            ((uint4*)dst)[q] = make_uint4(packbuf[4*q], packbuf[4*q+1],
                                          packbuf[4*q+2], packbuf[4*q+3]);
        }
    }
}

// ---------------------------------------------------------------------------
// Kernel 2: out[M][512] = S[M][128](bf16) x Wt[512][128](bf16, k-major B).
// Block = 256 thr (4 waves, 2x2), block tile 128x128, wave tile 64x64.
// Fragments loaded directly from global (layouts already match MFMA).
// ---------------------------------------------------------------------------
__global__ __launch_bounds__(256) void gemm_kernel(const uint16_t* __restrict__ S,
                                                   const uint16_t* __restrict__ Wt,
                                                   float* __restrict__ out) {
    int bid   = blockIdx.x;
    int ntile = bid & 3;
    int mtile = bid >> 2;
    int wave  = threadIdx.x >> 6;
    int lane  = threadIdx.x & 63;
    int wm    = wave >> 1, wn = wave & 1;
    int row0  = mtile * 128 + wm * 64;
    int col0  = ntile * 128 + wn * 64;
    int lm    = lane & 15;
    int lk    = (lane >> 4) * 8;

    floatx4 acc[4][4] = {};

    #pragma unroll
    for (int ks = 0; ks < 4; ++ks) {
        int k0 = ks * 32 + lk;
        bf16x8 afr[4], bfr[4];
        #pragma unroll
        for (int i = 0; i < 4; ++i)
            afr[i] = *(const bf16x8*)(S + (size_t)(row0 + i * 16 + lm) * P_ + k0);
        #pragma unroll
        for (int i = 0; i < 4; ++i)
            bfr[i] = *(const bf16x8*)(Wt + (size_t)(col0 + i * 16 + lm) * P_ + k0);
        #pragma unroll
        for (int i = 0; i < 4; ++i)
            #pragma unroll
            for (int j = 0; j < 4; ++j)
                acc[i][j] = __builtin_amdgcn_mfma_f32_16x16x32_bf16(
                    afr[i], bfr[j], acc[i][j], 0, 0, 0);
    }

    int rlane = (lane >> 4) * 4;   // D layout: row=(lane>>4)*4+reg, col=lane&15
    #pragma unroll
    for (int i = 0; i < 4; ++i)
        #pragma unroll
        for (int j = 0; j < 4; ++j)
            #pragma unroll
            for (int r = 0; r < 4; ++r) {
                int row = row0 + i * 16 + rlane + r;
                int col = col0 + j * 16 + lm;
                out[(size_t)row * D_ + col] = acc[i][j][r];
            }
}

// ---------------------------------------------------------------------------
extern "C" void kernel_launch(void* const* d_in, const int* in_sizes, int n_in,
                              void* d_out, int out_size, void* d_ws, size_t ws_size,
                              hipStream_t stream) {
    const float* x     = (const float*)d_in[0];
    // d_in[1] = x_mark, unused by the reference computation
    const float* alpha = (const float*)d_in[2];
    const float* W     = (const float*)d_in[3];

    float* out        = (float*)d_out;
    float* season_out = out;                          // [M][512] f32
    float* trend_out  = out + (size_t)M_ * D_;        // [b][c][l] f32

    uint32_t* season_ws = (uint32_t*)d_ws;            // [M][128] bf16 = 134,217,728 B
    uint16_t* Wt = (uint16_t*)((char*)d_ws + (size_t)M_ * P_ * 2);  // 131,072 B

    wt_kernel <<<256,   256, 0, stream>>>(W, Wt);
    ema_kernel<<<1024,  256, 0, stream>>>(x, alpha, trend_out, season_ws);
    gemm_kernel<<<16384, 256, 0, stream>>>((const uint16_t*)season_ws, Wt, season_out);
}